// Round 6
// baseline (1414.602 us; speedup 1.0000x reference)
//
#include <hip/hip_runtime.h>
#include <math.h>

#define NN   100000
#define EE   1200000
#define GG   128
#define FIN  16
#define HH   64
#define OUTF 5
#define NHID 3

// ---------------- wave helpers ----------------
static __device__ __forceinline__ float wave_reduce_sum(float p) {
#pragma unroll
  for (int m = 32; m >= 1; m >>= 1) p += __shfl_xor(p, m, 64);
  return p;
}
static __device__ __forceinline__ float wave_reduce_max(float p) {
#pragma unroll
  for (int m = 32; m >= 1; m >>= 1) p = fmaxf(p, __shfl_xor(p, m, 64));
  return p;
}

// ---------------- CSR build ----------------
__global__ void k_count(const int* __restrict__ ei, int* __restrict__ deg, int e) {
  int t = blockIdx.x * blockDim.x + threadIdx.x;
  if (t < e) atomicAdd(&deg[ei[EE + t]], 1);   // dst row is second row
}

// 1024 elements per block, 256 threads x 4
__global__ void k_scan1(const int* __restrict__ deg, int* __restrict__ incl,
                        int* __restrict__ bsum, int n) {
  __shared__ int sd[256];
  int t = threadIdx.x, blk = blockIdx.x;
  int base = blk * 1024 + t * 4;
  int v[4];
#pragma unroll
  for (int i = 0; i < 4; i++) v[i] = (base + i < n) ? deg[base + i] : 0;
  int s = v[0] + v[1] + v[2] + v[3];
  sd[t] = s;
  __syncthreads();
  for (int off = 1; off < 256; off <<= 1) {
    int x = 0;
    if (t >= off) x = sd[t - off];
    __syncthreads();
    if (t >= off) sd[t] += x;
    __syncthreads();
  }
  int run = sd[t] - s;  // exclusive prefix of this thread within block
#pragma unroll
  for (int i = 0; i < 4; i++) {
    run += v[i];
    if (base + i < n) incl[base + i] = run;
  }
  if (t == 255) bsum[blk] = sd[255];
}

__global__ void k_scan2(const int* __restrict__ bsum, int* __restrict__ boff, int nb) {
  if (threadIdx.x == 0 && blockIdx.x == 0) {
    int run = 0;
    for (int i = 0; i < nb; i++) { boff[i] = run; run += bsum[i]; }
  }
}

__global__ void k_scan3(const int* __restrict__ incl, const int* __restrict__ boff,
                        const int* __restrict__ deg, int* __restrict__ row_ptr,
                        int* __restrict__ wix, int n) {
  int t = blockIdx.x * blockDim.x + threadIdx.x;
  if (t < n) {
    int v = incl[t] + boff[t / 1024];  // global inclusive scan
    row_ptr[t + 1] = v;
    wix[t] = v - deg[t];               // global exclusive scan = write cursor
  }
  if (t == 0) row_ptr[0] = 0;
}

__global__ void k_scatter(const int* __restrict__ ei, int* __restrict__ wix,
                          int* __restrict__ col, int* __restrict__ dstarr, int e) {
  int t = blockIdx.x * blockDim.x + threadIdx.x;
  if (t < e) {
    int d = ei[EE + t];
    int s = ei[t];
    int pos = atomicAdd(&wix[d], 1);
    col[pos] = s;
    dstarr[pos] = d;
  }
}

// ---------------- projections: lane = node, w via scalar pipe ----------------
// Block = 4 waves; wave m computes matrix m in {q,k,v,skip} for the SAME
// 64-node tile. x staged k-major in LDS (pad 69: staging writes and per-k
// reads are both 2-way = free); per k: ONE lane-varying ds_read_b32 feeds
// all 64 lanes (lane = node), w row is wave-uniform -> s_load on the scalar
// pipe, FMA takes the SGPR operand. Output transposed through a per-wave
// 16x65 LDS buffer into fully-coalesced 64B-aligned stores.
// LDS pipe per block drops from 4096 b128 (R4/R5: 49k cyc -> 116us wall) to
// ~64 b32/wave + epilogue: VALU-FMA becomes the limiter (~21us floor).
template <int F>
__global__ __launch_bounds__(256) void k_gemm(
    const float* __restrict__ X,
    const float* __restrict__ Wq, const float* __restrict__ bq,
    const float* __restrict__ Wk, const float* __restrict__ bk,
    const float* __restrict__ Wv, const float* __restrict__ bv,
    const float* __restrict__ Ws, const float* __restrict__ bs,
    float* __restrict__ q, float* __restrict__ k, float* __restrict__ v,
    float* __restrict__ B, int n) {
  __shared__ float xs[F * 69];
  __shared__ float wb[4][16 * 65];
  int tid = threadIdx.x;
  int lane = tid & 63;
  int m = tid >> 6;
  int node0 = blockIdx.x * 64;
  int cnt = min(64, n - node0);
  if (cnt <= 0) return;

  // stage X tile, transposed to k-major (coalesced global float4 reads;
  // LDS writes: banks (20j+5i+n)%32 -> exactly 2-way, free)
  {
    const float4* xg = (const float4*)(X + (size_t)node0 * F);
    int total4 = (cnt * F) >> 2;
    for (int f = tid; f < total4; f += 256) {
      float4 p = xg[f];
      int nn = f / (F / 4);
      int kb = (f % (F / 4)) << 2;
      xs[(kb + 0) * 69 + nn] = p.x;
      xs[(kb + 1) * 69 + nn] = p.y;
      xs[(kb + 2) * 69 + nn] = p.z;
      xs[(kb + 3) * 69 + nn] = p.w;
    }
  }

  const float* W; const float* bias; float* out;
  if (m == 0)      { W = Wq; bias = bq; out = q; }
  else if (m == 1) { W = Wk; bias = bk; out = k; }
  else if (m == 2) { W = Wv; bias = bv; out = v; }
  else             { W = Ws; bias = bs; out = B; }

  float acc[64];
#pragma unroll
  for (int c = 0; c < 64; ++c) acc[c] = bias[c];

  __syncthreads();

  float xk = xs[lane];
  for (int kk2 = 0; kk2 < F; ++kk2) {
    float xn = (kk2 + 1 < F) ? xs[(kk2 + 1) * 69 + lane] : 0.f;
    int ko = __builtin_amdgcn_readfirstlane(kk2) << 6;
    const float* wr = W + ko;
#pragma unroll
    for (int c = 0; c < 32; ++c) acc[c] = fmaf(xk, wr[c], acc[c]);
#pragma unroll
    for (int c = 32; c < 64; ++c) acc[c] = fmaf(xk, wr[c], acc[c]);
    xk = xn;
  }

  // epilogue: per-wave LDS transpose -> coalesced stores
  float* wbw = wb[m];
  int nn = lane >> 2;          // 0..15
  int ci = (lane & 3) << 2;    // 0,4,8,12
#pragma unroll
  for (int c0 = 0; c0 < 64; c0 += 16) {
#pragma unroll
    for (int c2 = 0; c2 < 16; ++c2) wbw[c2 * 65 + lane] = acc[c0 + c2];
#pragma unroll
    for (int r = 0; r < 4; ++r) {
      int node = r * 16 + nn;
      float4 o;
      o.x = wbw[(ci + 0) * 65 + node];
      o.y = wbw[(ci + 1) * 65 + node];
      o.z = wbw[(ci + 2) * 65 + node];
      o.w = wbw[(ci + 3) * 65 + node];
      if (node < cnt)
        *(float4*)(out + (size_t)(node0 + node) * 64 + c0 + ci) = o;
    }
  }
}

// ---------------- attention phase A: per-edge scores (CSR order) ----------------
// 16 lanes per edge, 4 edges per wave. s[p] = dot(q[dst[p]], k[src[p]]) / 8
__global__ __launch_bounds__(256) void k_score(
    const float* __restrict__ q, const float* __restrict__ k,
    const int* __restrict__ col, const int* __restrict__ dstarr,
    float* __restrict__ s, int e) {
  int wid = (blockIdx.x * 256 + threadIdx.x) >> 6;
  int lane = threadIdx.x & 63;
  int sub = lane >> 4, li = lane & 15;
  int p = wid * 4 + sub;
  if (p >= e) return;
  int sn = col[p];
  int dn = dstarr[p];
  float4 a = ((const float4*)(q + (size_t)dn * 64))[li];
  float4 b = ((const float4*)(k + (size_t)sn * 64))[li];
  float dot = a.x * b.x + a.y * b.y + a.z * b.z + a.w * b.w;
#pragma unroll
  for (int mm = 8; mm >= 1; mm >>= 1) dot += __shfl_xor(dot, mm, 64);
  if (li == 0) s[p] = dot * 0.125f;  // 1/sqrt(64)
}

// ---------------- attention phase B: per-dst softmax + V aggregation ----------------
__global__ __launch_bounds__(256) void k_aggr(
    const float* __restrict__ s, const float* __restrict__ v,
    const int* __restrict__ row_ptr, const int* __restrict__ col,
    float* __restrict__ B, int n) {
  int d = blockIdx.x * 4 + (threadIdx.x >> 6);
  int lane = threadIdx.x & 63;
  if (d >= n) return;
  int e0 = row_ptr[d], e1 = row_ptr[d + 1];
  const float NEG = -__builtin_huge_valf();
  float m = NEG, l = 0.f;
  float a0 = 0.f, a1 = 0.f, a2 = 0.f, a3 = 0.f;
  for (int c = e0; c < e1; c += 64) {
    int cnt = min(64, e1 - c);
    bool act = lane < cnt;
    float sv = act ? s[c + lane] : NEG;
    int sc = act ? col[c + lane] : 0;
    float mc = wave_reduce_max(sv);
    float mn = fmaxf(m, mc);
    float rf = __expf(m - mn);  // 0 on first chunk (m = -inf)
    float pe = act ? __expf(sv - mn) : 0.f;
    float ls = wave_reduce_sum(pe);
    l = fmaf(l, rf, ls);
    a0 *= rf; a1 *= rf; a2 *= rf; a3 *= rf;
    int i = 0;
    for (; i + 3 < cnt; i += 4) {
      int s0 = __shfl(sc, i, 64);     float w0 = __shfl(pe, i, 64);
      int s1 = __shfl(sc, i + 1, 64); float w1 = __shfl(pe, i + 1, 64);
      int s2 = __shfl(sc, i + 2, 64); float w2 = __shfl(pe, i + 2, 64);
      int s3 = __shfl(sc, i + 3, 64); float w3 = __shfl(pe, i + 3, 64);
      float v0 = v[(size_t)s0 * 64 + lane];
      float v1 = v[(size_t)s1 * 64 + lane];
      float v2 = v[(size_t)s2 * 64 + lane];
      float v3 = v[(size_t)s3 * 64 + lane];
      a0 = fmaf(w0, v0, a0);
      a1 = fmaf(w1, v1, a1);
      a2 = fmaf(w2, v2, a2);
      a3 = fmaf(w3, v3, a3);
    }
    for (; i < cnt; ++i) {
      int s0 = __shfl(sc, i, 64);
      float w0 = __shfl(pe, i, 64);
      a0 = fmaf(w0, v[(size_t)s0 * 64 + lane], a0);
    }
    m = mn;
  }
  float acc = (a0 + a1) + (a2 + a3);
  size_t o = (size_t)d * 64 + lane;
  B[o] += acc / (l + 1e-16f);  // B pre-holds the skip term
}

// ---------------- pooling ----------------
__global__ void k_bounds(const int* __restrict__ batch, int* __restrict__ sp,
                         int* __restrict__ ep, int n) {
  int t = blockIdx.x * blockDim.x + threadIdx.x;
  if (t >= n) return;
  int g = batch[t];
  if (t == 0 || batch[t - 1] != g) sp[g] = t;
  if (t == n - 1 || batch[t + 1] != g) ep[g] = t + 1;
}

__global__ __launch_bounds__(256) void k_pool(
    const float* __restrict__ H, const int* __restrict__ batch,
    float* __restrict__ pooled, int n) {
  int lane = threadIdx.x & 63;
  int w = threadIdx.x >> 6;
  int n0 = blockIdx.x * 64 + w * 16;
  float acc = 0.f;
  int cur = -1;
  for (int i = 0; i < 16; i++) {
    int node = n0 + i;
    if (node >= n) break;
    int g = batch[node];
    if (g != cur) {
      if (cur >= 0) atomicAdd(&pooled[cur * 64 + lane], acc);
      cur = g;
      acc = 0.f;
    }
    acc += H[(size_t)node * 64 + lane];
  }
  if (cur >= 0) atomicAdd(&pooled[cur * 64 + lane], acc);
}

__global__ void k_out(const float* __restrict__ pooled, const int* __restrict__ sp,
                      const int* __restrict__ ep, const float* __restrict__ Wf,
                      const float* __restrict__ bf, float* __restrict__ out) {
  int g = blockIdx.x;
  int lane = threadIdx.x;  // 64 threads
  int c = ep[g] - sp[g];
  float cf = (float)(c > 1 ? c : 1);
  float mean = pooled[g * 64 + lane] / cf;
#pragma unroll
  for (int o = 0; o < OUTF; o++) {
    float p = wave_reduce_sum(mean * Wf[lane * OUTF + o]);
    if (lane == 0) out[g * OUTF + o] = p + bf[o];
  }
}

// ---------------- launch ----------------
extern "C" void kernel_launch(void* const* d_in, const int* in_sizes, int n_in,
                              void* d_out, int out_size, void* d_ws, size_t ws_size,
                              hipStream_t stream) {
  const float* x   = (const float*)d_in[0];
  const int* ei    = (const int*)d_in[1];
  const int* batch = (const int*)d_in[2];
  const float *Wq0 = (const float*)d_in[3],  *bq0 = (const float*)d_in[4];
  const float *Wk0 = (const float*)d_in[5],  *bk0 = (const float*)d_in[6];
  const float *Wv0 = (const float*)d_in[7],  *bv0 = (const float*)d_in[8];
  const float *Ws0 = (const float*)d_in[9],  *bs0 = (const float*)d_in[10];
  const float *Wqh = (const float*)d_in[11], *bqh = (const float*)d_in[12];
  const float *Wkh = (const float*)d_in[13], *bkh = (const float*)d_in[14];
  const float *Wvh = (const float*)d_in[15], *bvh = (const float*)d_in[16];
  const float *Wsh = (const float*)d_in[17], *bsh = (const float*)d_in[18];
  const float *Wf  = (const float*)d_in[19], *bf  = (const float*)d_in[20];

  float* q  = (float*)d_ws;
  float* kk = q  + (size_t)NN * 64;
  float* vv = kk + (size_t)NN * 64;
  float* B0 = vv + (size_t)NN * 64;
  float* B1 = B0 + (size_t)NN * 64;
  float* sc = B1 + (size_t)NN * 64;         // per-edge scores, CSR order
  float* pooled = sc + EE;
  int* deg     = (int*)(pooled + GG * 64);
  int* row_ptr = deg + NN;
  int* incl    = row_ptr + NN + 1;
  int* bsum    = incl + NN;
  int* boff    = bsum + 128;
  int* wix     = boff + 128;
  int* col     = wix + NN;
  int* dstarr  = col + EE;
  int* sp      = dstarr + EE;
  int* ep      = sp + GG;

  hipMemsetAsync(deg, 0, NN * sizeof(int), stream);
  hipMemsetAsync(pooled, 0, GG * 64 * sizeof(float), stream);
  hipMemsetAsync(sp, 0, 2 * GG * sizeof(int), stream);

  // CSR build (once per call; reused by all 4 layers)
  k_count<<<(EE + 255) / 256, 256, 0, stream>>>(ei, deg, EE);
  int nb = (NN + 1023) / 1024;
  k_scan1<<<nb, 256, 0, stream>>>(deg, incl, bsum, NN);
  k_scan2<<<1, 64, 0, stream>>>(bsum, boff, nb);
  k_scan3<<<(NN + 255) / 256, 256, 0, stream>>>(incl, boff, deg, row_ptr, wix, NN);
  k_scatter<<<(EE + 255) / 256, 256, 0, stream>>>(ei, wix, col, dstarr, EE);

  int gg = (NN + 63) / 64;
  int ga = (NN + 3) / 4;
  int ge = ((EE + 3) / 4 + 3) / 4;  // 4 edges/wave, 4 waves/block

  // layer 0 (F_IN=16)
  k_gemm<FIN><<<gg, 256, 0, stream>>>(x, Wq0, bq0, Wk0, bk0, Wv0, bv0, Ws0, bs0,
                                      q, kk, vv, B0, NN);
  k_score<<<ge, 256, 0, stream>>>(q, kk, col, dstarr, sc, EE);
  k_aggr<<<ga, 256, 0, stream>>>(sc, vv, row_ptr, col, B0, NN);

  // hidden layers (H=64), ping-pong B0 <-> B1
  const float* hin = B0;
  float* hout = B1;
  for (int i = 0; i < NHID; i++) {
    k_gemm<HH><<<gg, 256, 0, stream>>>(hin, Wqh + i * 4096, bqh + i * 64,
                                       Wkh + i * 4096, bkh + i * 64,
                                       Wvh + i * 4096, bvh + i * 64,
                                       Wsh + i * 4096, bsh + i * 64,
                                       q, kk, vv, hout, NN);
    k_score<<<ge, 256, 0, stream>>>(q, kk, col, dstarr, sc, EE);
    k_aggr<<<ga, 256, 0, stream>>>(sc, vv, row_ptr, col, hout, NN);
    float* t = (float*)hin; hin = hout; hout = t;
  }
  // hin now points at the final hidden features

  k_bounds<<<(NN + 255) / 256, 256, 0, stream>>>(batch, sp, ep, NN);
  k_pool<<<(NN + 63) / 64, 256, 0, stream>>>(hin, batch, pooled, NN);
  k_out<<<GG, 64, 0, stream>>>(pooled, sp, ep, Wf, bf, (float*)d_out);
}

// Round 7
// 957.604 us; speedup vs baseline: 1.4772x; 1.4772x over previous
//
#include <hip/hip_runtime.h>
#include <math.h>

#define NN   100000
#define EE   1200000
#define GG   128
#define FIN  16
#define HH   64
#define OUTF 5
#define NHID 3
#define CHUNK 32   // nodes per wave in k_gemm

// ---------------- wave helpers ----------------
static __device__ __forceinline__ float wave_reduce_sum(float p) {
#pragma unroll
  for (int m = 32; m >= 1; m >>= 1) p += __shfl_xor(p, m, 64);
  return p;
}
static __device__ __forceinline__ float wave_reduce_max(float p) {
#pragma unroll
  for (int m = 32; m >= 1; m >>= 1) p = fmaxf(p, __shfl_xor(p, m, 64));
  return p;
}

// ---------------- CSR build ----------------
__global__ void k_count(const int* __restrict__ ei, int* __restrict__ deg, int e) {
  int t = blockIdx.x * blockDim.x + threadIdx.x;
  if (t < e) atomicAdd(&deg[ei[EE + t]], 1);   // dst row is second row
}

// 1024 elements per block, 256 threads x 4
__global__ void k_scan1(const int* __restrict__ deg, int* __restrict__ incl,
                        int* __restrict__ bsum, int n) {
  __shared__ int sd[256];
  int t = threadIdx.x, blk = blockIdx.x;
  int base = blk * 1024 + t * 4;
  int v[4];
#pragma unroll
  for (int i = 0; i < 4; i++) v[i] = (base + i < n) ? deg[base + i] : 0;
  int s = v[0] + v[1] + v[2] + v[3];
  sd[t] = s;
  __syncthreads();
  for (int off = 1; off < 256; off <<= 1) {
    int x = 0;
    if (t >= off) x = sd[t - off];
    __syncthreads();
    if (t >= off) sd[t] += x;
    __syncthreads();
  }
  int run = sd[t] - s;  // exclusive prefix of this thread within block
#pragma unroll
  for (int i = 0; i < 4; i++) {
    run += v[i];
    if (base + i < n) incl[base + i] = run;
  }
  if (t == 255) bsum[blk] = sd[255];
}

__global__ void k_scan2(const int* __restrict__ bsum, int* __restrict__ boff, int nb) {
  if (threadIdx.x == 0 && blockIdx.x == 0) {
    int run = 0;
    for (int i = 0; i < nb; i++) { boff[i] = run; run += bsum[i]; }
  }
}

__global__ void k_scan3(const int* __restrict__ incl, const int* __restrict__ boff,
                        const int* __restrict__ deg, int* __restrict__ row_ptr,
                        int* __restrict__ wix, int n) {
  int t = blockIdx.x * blockDim.x + threadIdx.x;
  if (t < n) {
    int v = incl[t] + boff[t / 1024];  // global inclusive scan
    row_ptr[t + 1] = v;
    wix[t] = v - deg[t];               // global exclusive scan = write cursor
  }
  if (t == 0) row_ptr[0] = 0;
}

__global__ void k_scatter(const int* __restrict__ ei, int* __restrict__ wix,
                          int* __restrict__ col, int* __restrict__ dstarr, int e) {
  int t = blockIdx.x * blockDim.x + threadIdx.x;
  if (t < e) {
    int d = ei[EE + t];
    int s = ei[t];
    int pos = atomicAdd(&wix[d], 1);
    col[pos] = s;
    dstarr[pos] = d;
  }
}

// ---------------- projections: wave-per-node-group, 2 matrices/wave --------
// R2/R3-proven structure (105us), plus: each wave computes TWO output
// matrices from the same x loads -> 2x FMA per load-stall, X fetched 2x
// instead of 4x. gridDim.y: 0 -> {q,k}, 1 -> {v,skip}. x rows read at
// wave-uniform addresses (readfirstlane -> s_load batches); stores fully
// coalesced (out[node*64+lane], 256B/wave). R5's lane=node + per-k s_load
// design is abandoned (serial SMEM latency per k, 2 blocks/CU -> 225us).
template <int F>
__global__ __launch_bounds__(256) void k_gemm(
    const float* __restrict__ X,
    const float* __restrict__ Wq, const float* __restrict__ bq,
    const float* __restrict__ Wk, const float* __restrict__ bk,
    const float* __restrict__ Wv, const float* __restrict__ bv,
    const float* __restrict__ Ws, const float* __restrict__ bs,
    float* __restrict__ q, float* __restrict__ k, float* __restrict__ v,
    float* __restrict__ B, int n) {
  int lane = threadIdx.x & 63;
  int wib = threadIdx.x >> 6;
  const float *W0, *b0v, *W1, *b1v;
  float *out0, *out1;
  if (blockIdx.y == 0) {
    W0 = Wq; b0v = bq; out0 = q;
    W1 = Wk; b1v = bk; out1 = k;
  } else {
    W0 = Wv; b0v = bv; out0 = v;
    W1 = Ws; b1v = bs; out1 = B;
  }
  float w0[F], w1[F];
#pragma unroll
  for (int i = 0; i < F; i++) w0[i] = W0[i * 64 + lane];
#pragma unroll
  for (int i = 0; i < F; i++) w1[i] = W1[i * 64 + lane];
  float bl0 = b0v[lane], bl1 = b1v[lane];
  int node0 = (blockIdx.x * 4 + wib) * CHUNK;
  if (node0 >= n) return;
#pragma unroll 1
  for (int nb = 0; nb < CHUNK; nb += 4) {
    int n0 = node0 + nb;
    if (n0 >= n) return;
    if (n0 + 4 <= n) {
      int u0 = __builtin_amdgcn_readfirstlane(n0);
      const float* x0 = X + (size_t)u0 * F;
      const float* x1 = x0 + F;
      const float* x2 = x1 + F;
      const float* x3 = x2 + F;
      float a0 = bl0, a1 = bl0, a2 = bl0, a3 = bl0;
      float c0 = bl1, c1 = bl1, c2 = bl1, c3 = bl1;
#pragma unroll
      for (int i = 0; i < F; i += 4) {
        float4 p0 = *(const float4*)(x0 + i);
        float4 p1 = *(const float4*)(x1 + i);
        float4 p2 = *(const float4*)(x2 + i);
        float4 p3 = *(const float4*)(x3 + i);
        a0 = fmaf(p0.x, w0[i], a0);     a1 = fmaf(p1.x, w0[i], a1);
        a2 = fmaf(p2.x, w0[i], a2);     a3 = fmaf(p3.x, w0[i], a3);
        c0 = fmaf(p0.x, w1[i], c0);     c1 = fmaf(p1.x, w1[i], c1);
        c2 = fmaf(p2.x, w1[i], c2);     c3 = fmaf(p3.x, w1[i], c3);
        a0 = fmaf(p0.y, w0[i + 1], a0); a1 = fmaf(p1.y, w0[i + 1], a1);
        a2 = fmaf(p2.y, w0[i + 1], a2); a3 = fmaf(p3.y, w0[i + 1], a3);
        c0 = fmaf(p0.y, w1[i + 1], c0); c1 = fmaf(p1.y, w1[i + 1], c1);
        c2 = fmaf(p2.y, w1[i + 1], c2); c3 = fmaf(p3.y, w1[i + 1], c3);
        a0 = fmaf(p0.z, w0[i + 2], a0); a1 = fmaf(p1.z, w0[i + 2], a1);
        a2 = fmaf(p2.z, w0[i + 2], a2); a3 = fmaf(p3.z, w0[i + 2], a3);
        c0 = fmaf(p0.z, w1[i + 2], c0); c1 = fmaf(p1.z, w1[i + 2], c1);
        c2 = fmaf(p2.z, w1[i + 2], c2); c3 = fmaf(p3.z, w1[i + 2], c3);
        a0 = fmaf(p0.w, w0[i + 3], a0); a1 = fmaf(p1.w, w0[i + 3], a1);
        a2 = fmaf(p2.w, w0[i + 3], a2); a3 = fmaf(p3.w, w0[i + 3], a3);
        c0 = fmaf(p0.w, w1[i + 3], c0); c1 = fmaf(p1.w, w1[i + 3], c1);
        c2 = fmaf(p2.w, w1[i + 3], c2); c3 = fmaf(p3.w, w1[i + 3], c3);
      }
      size_t o = (size_t)u0 * 64 + lane;
      out0[o] = a0; out0[o + 64] = a1; out0[o + 128] = a2; out0[o + 192] = a3;
      out1[o] = c0; out1[o + 64] = c1; out1[o + 128] = c2; out1[o + 192] = c3;
    } else {
      for (int nn = n0; nn < n; nn++) {
        int u = __builtin_amdgcn_readfirstlane(nn);
        const float* xr = X + (size_t)u * F;
        float a = bl0, c = bl1;
#pragma unroll
        for (int i = 0; i < F; i++) {
          a = fmaf(xr[i], w0[i], a);
          c = fmaf(xr[i], w1[i], c);
        }
        out0[(size_t)u * 64 + lane] = a;
        out1[(size_t)u * 64 + lane] = c;
      }
      return;
    }
  }
}

// ---------------- attention phase A: per-edge scores (CSR order) ----------------
// 16 lanes per edge, 4 edges per wave. s[p] = dot(q[dst[p]], k[src[p]]) / 8
__global__ __launch_bounds__(256) void k_score(
    const float* __restrict__ q, const float* __restrict__ k,
    const int* __restrict__ col, const int* __restrict__ dstarr,
    float* __restrict__ s, int e) {
  int wid = (blockIdx.x * 256 + threadIdx.x) >> 6;
  int lane = threadIdx.x & 63;
  int sub = lane >> 4, li = lane & 15;
  int p = wid * 4 + sub;
  if (p >= e) return;
  int sn = col[p];
  int dn = dstarr[p];
  float4 a = ((const float4*)(q + (size_t)dn * 64))[li];
  float4 b = ((const float4*)(k + (size_t)sn * 64))[li];
  float dot = a.x * b.x + a.y * b.y + a.z * b.z + a.w * b.w;
#pragma unroll
  for (int mm = 8; mm >= 1; mm >>= 1) dot += __shfl_xor(dot, mm, 64);
  if (li == 0) s[p] = dot * 0.125f;  // 1/sqrt(64)
}

// ---------------- attention phase B: per-dst softmax + V aggregation ----------------
__global__ __launch_bounds__(256) void k_aggr(
    const float* __restrict__ s, const float* __restrict__ v,
    const int* __restrict__ row_ptr, const int* __restrict__ col,
    float* __restrict__ B, int n) {
  int d = blockIdx.x * 4 + (threadIdx.x >> 6);
  int lane = threadIdx.x & 63;
  if (d >= n) return;
  int e0 = row_ptr[d], e1 = row_ptr[d + 1];
  const float NEG = -__builtin_huge_valf();
  float m = NEG, l = 0.f;
  float a0 = 0.f, a1 = 0.f, a2 = 0.f, a3 = 0.f;
  for (int c = e0; c < e1; c += 64) {
    int cnt = min(64, e1 - c);
    bool act = lane < cnt;
    float sv = act ? s[c + lane] : NEG;
    int sc = act ? col[c + lane] : 0;
    float mc = wave_reduce_max(sv);
    float mn = fmaxf(m, mc);
    float rf = __expf(m - mn);  // 0 on first chunk (m = -inf)
    float pe = act ? __expf(sv - mn) : 0.f;
    float ls = wave_reduce_sum(pe);
    l = fmaf(l, rf, ls);
    a0 *= rf; a1 *= rf; a2 *= rf; a3 *= rf;
    int i = 0;
    for (; i + 3 < cnt; i += 4) {
      int s0 = __shfl(sc, i, 64);     float w0 = __shfl(pe, i, 64);
      int s1 = __shfl(sc, i + 1, 64); float w1 = __shfl(pe, i + 1, 64);
      int s2 = __shfl(sc, i + 2, 64); float w2 = __shfl(pe, i + 2, 64);
      int s3 = __shfl(sc, i + 3, 64); float w3 = __shfl(pe, i + 3, 64);
      float v0 = v[(size_t)s0 * 64 + lane];
      float v1 = v[(size_t)s1 * 64 + lane];
      float v2 = v[(size_t)s2 * 64 + lane];
      float v3 = v[(size_t)s3 * 64 + lane];
      a0 = fmaf(w0, v0, a0);
      a1 = fmaf(w1, v1, a1);
      a2 = fmaf(w2, v2, a2);
      a3 = fmaf(w3, v3, a3);
    }
    for (; i < cnt; ++i) {
      int s0 = __shfl(sc, i, 64);
      float w0 = __shfl(pe, i, 64);
      a0 = fmaf(w0, v[(size_t)s0 * 64 + lane], a0);
    }
    m = mn;
  }
  float acc = (a0 + a1) + (a2 + a3);
  size_t o = (size_t)d * 64 + lane;
  B[o] += acc / (l + 1e-16f);  // B pre-holds the skip term
}

// ---------------- pooling ----------------
__global__ void k_bounds(const int* __restrict__ batch, int* __restrict__ sp,
                         int* __restrict__ ep, int n) {
  int t = blockIdx.x * blockDim.x + threadIdx.x;
  if (t >= n) return;
  int g = batch[t];
  if (t == 0 || batch[t - 1] != g) sp[g] = t;
  if (t == n - 1 || batch[t + 1] != g) ep[g] = t + 1;
}

__global__ __launch_bounds__(256) void k_pool(
    const float* __restrict__ H, const int* __restrict__ batch,
    float* __restrict__ pooled, int n) {
  int lane = threadIdx.x & 63;
  int w = threadIdx.x >> 6;
  int n0 = blockIdx.x * 64 + w * 16;
  float acc = 0.f;
  int cur = -1;
  for (int i = 0; i < 16; i++) {
    int node = n0 + i;
    if (node >= n) break;
    int g = batch[node];
    if (g != cur) {
      if (cur >= 0) atomicAdd(&pooled[cur * 64 + lane], acc);
      cur = g;
      acc = 0.f;
    }
    acc += H[(size_t)node * 64 + lane];
  }
  if (cur >= 0) atomicAdd(&pooled[cur * 64 + lane], acc);
}

__global__ void k_out(const float* __restrict__ pooled, const int* __restrict__ sp,
                      const int* __restrict__ ep, const float* __restrict__ Wf,
                      const float* __restrict__ bf, float* __restrict__ out) {
  int g = blockIdx.x;
  int lane = threadIdx.x;  // 64 threads
  int c = ep[g] - sp[g];
  float cf = (float)(c > 1 ? c : 1);
  float mean = pooled[g * 64 + lane] / cf;
#pragma unroll
  for (int o = 0; o < OUTF; o++) {
    float p = wave_reduce_sum(mean * Wf[lane * OUTF + o]);
    if (lane == 0) out[g * OUTF + o] = p + bf[o];
  }
}

// ---------------- launch ----------------
extern "C" void kernel_launch(void* const* d_in, const int* in_sizes, int n_in,
                              void* d_out, int out_size, void* d_ws, size_t ws_size,
                              hipStream_t stream) {
  const float* x   = (const float*)d_in[0];
  const int* ei    = (const int*)d_in[1];
  const int* batch = (const int*)d_in[2];
  const float *Wq0 = (const float*)d_in[3],  *bq0 = (const float*)d_in[4];
  const float *Wk0 = (const float*)d_in[5],  *bk0 = (const float*)d_in[6];
  const float *Wv0 = (const float*)d_in[7],  *bv0 = (const float*)d_in[8];
  const float *Ws0 = (const float*)d_in[9],  *bs0 = (const float*)d_in[10];
  const float *Wqh = (const float*)d_in[11], *bqh = (const float*)d_in[12];
  const float *Wkh = (const float*)d_in[13], *bkh = (const float*)d_in[14];
  const float *Wvh = (const float*)d_in[15], *bvh = (const float*)d_in[16];
  const float *Wsh = (const float*)d_in[17], *bsh = (const float*)d_in[18];
  const float *Wf  = (const float*)d_in[19], *bf  = (const float*)d_in[20];

  float* q  = (float*)d_ws;
  float* kk = q  + (size_t)NN * 64;
  float* vv = kk + (size_t)NN * 64;
  float* B0 = vv + (size_t)NN * 64;
  float* B1 = B0 + (size_t)NN * 64;
  float* sc = B1 + (size_t)NN * 64;         // per-edge scores, CSR order
  float* pooled = sc + EE;
  int* deg     = (int*)(pooled + GG * 64);
  int* row_ptr = deg + NN;
  int* incl    = row_ptr + NN + 1;
  int* bsum    = incl + NN;
  int* boff    = bsum + 128;
  int* wix     = boff + 128;
  int* col     = wix + NN;
  int* dstarr  = col + EE;
  int* sp      = dstarr + EE;
  int* ep      = sp + GG;

  hipMemsetAsync(deg, 0, NN * sizeof(int), stream);
  hipMemsetAsync(pooled, 0, GG * 64 * sizeof(float), stream);
  hipMemsetAsync(sp, 0, 2 * GG * sizeof(int), stream);

  // CSR build (once per call; reused by all 4 layers)
  k_count<<<(EE + 255) / 256, 256, 0, stream>>>(ei, deg, EE);
  int nb = (NN + 1023) / 1024;
  k_scan1<<<nb, 256, 0, stream>>>(deg, incl, bsum, NN);
  k_scan2<<<1, 64, 0, stream>>>(bsum, boff, nb);
  k_scan3<<<(NN + 255) / 256, 256, 0, stream>>>(incl, boff, deg, row_ptr, wix, NN);
  k_scatter<<<(EE + 255) / 256, 256, 0, stream>>>(ei, wix, col, dstarr, EE);

  dim3 gg((NN + 4 * CHUNK - 1) / (4 * CHUNK), 2);
  int ga = (NN + 3) / 4;
  int ge = ((EE + 3) / 4 + 3) / 4;  // 4 edges/wave, 4 waves/block

  // layer 0 (F_IN=16)
  k_gemm<FIN><<<gg, 256, 0, stream>>>(x, Wq0, bq0, Wk0, bk0, Wv0, bv0, Ws0, bs0,
                                      q, kk, vv, B0, NN);
  k_score<<<ge, 256, 0, stream>>>(q, kk, col, dstarr, sc, EE);
  k_aggr<<<ga, 256, 0, stream>>>(sc, vv, row_ptr, col, B0, NN);

  // hidden layers (H=64), ping-pong B0 <-> B1
  const float* hin = B0;
  float* hout = B1;
  for (int i = 0; i < NHID; i++) {
    k_gemm<HH><<<gg, 256, 0, stream>>>(hin, Wqh + i * 4096, bqh + i * 64,
                                       Wkh + i * 4096, bkh + i * 64,
                                       Wvh + i * 4096, bvh + i * 64,
                                       Wsh + i * 4096, bsh + i * 64,
                                       q, kk, vv, hout, NN);
    k_score<<<ge, 256, 0, stream>>>(q, kk, col, dstarr, sc, EE);
    k_aggr<<<ga, 256, 0, stream>>>(sc, vv, row_ptr, col, hout, NN);
    float* t = (float*)hin; hin = hout; hout = t;
  }
  // hin now points at the final hidden features

  k_bounds<<<(NN + 255) / 256, 256, 0, stream>>>(batch, sp, ep, NN);
  k_pool<<<(NN + 63) / 64, 256, 0, stream>>>(hin, batch, pooled, NN);
  k_out<<<GG, 64, 0, stream>>>(pooled, sp, ep, Wf, bf, (float*)d_out);
}